// Round 4
// baseline (994.846 us; speedup 1.0000x reference)
//
#include <hip/hip_runtime.h>
#include <type_traits>
#include <cstdint>
#include <cstddef>

// ---- types ----
typedef __bf16 bf16x8 __attribute__((ext_vector_type(8)));
typedef float  f32x4  __attribute__((ext_vector_type(4)));
typedef unsigned short u16v4 __attribute__((ext_vector_type(4)));
typedef unsigned short u16v8 __attribute__((ext_vector_type(8)));

#define H    2048
#define NH   16
#define NKV  8
#define HD   128
#define II   8192
#define S    2048

__device__ __forceinline__ unsigned short f2bf(float f) {
    union { float f; unsigned u; } v; v.f = f;
    unsigned r = v.u + 0x7fffu + ((v.u >> 16) & 1u);
    return (unsigned short)(r >> 16);
}
__device__ __forceinline__ float bf2f(unsigned short b) {
    union { unsigned u; float f; } v; v.u = ((unsigned)b) << 16;
    return v.f;
}

// async global->LDS, 16B per lane. LDS dest must be wave-uniform base;
// HW adds lane*16. [m97: this alone was 517->874 TF]
__device__ __forceinline__ void async16(const unsigned short* g, const unsigned short* l) {
    __builtin_amdgcn_global_load_lds(
        (const __attribute__((address_space(1))) void*)g,
        (__attribute__((address_space(3))) void*)l, 16, 0, 0);
}

// ---------------- weight fp32 -> bf16 (8 elems/thread) ----------------
__global__ __launch_bounds__(256) void w2bf(const float* __restrict__ src,
                                            unsigned short* __restrict__ dst)
{
    const size_t i = (size_t)blockIdx.x * 256 + threadIdx.x;
    float4 a = ((const float4*)src)[2 * i];
    float4 b = ((const float4*)src)[2 * i + 1];
    u16v8 o;
    o[0] = f2bf(a.x); o[1] = f2bf(a.y); o[2] = f2bf(a.z); o[3] = f2bf(a.w);
    o[4] = f2bf(b.x); o[5] = f2bf(b.y); o[6] = f2bf(b.z); o[7] = f2bf(b.w);
    ((u16v8*)dst)[i] = o;
}

// ---- mlp weights fp32 -> bf16 with up/gate interleave ----
// src: up [II][H] then gate [II][H].
// dst row p (0..2II-1): g=p>>7, r=p&127, half=r>>6 (0=up,1=gate), col c=g*64+(r&63)
// -> each 128-row B-tile g holds up rows c and gate rows of the SAME c.
__global__ __launch_bounds__(256) void w2bf_mlp(const float* __restrict__ src,
                                                unsigned short* __restrict__ dst)
{
    const int p = blockIdx.x;
    const int g = p >> 7, r = p & 127;
    const int half = r >> 6;
    const int c = (g << 6) + (r & 63);
    const float* s = src + ((size_t)half * II + c) * H;
    unsigned short* d = dst + (size_t)p * H;
    const int t = threadIdx.x;
    float4 a = ((const float4*)s)[2 * t];
    float4 b = ((const float4*)s)[2 * t + 1];
    u16v8 o;
    o[0] = f2bf(a.x); o[1] = f2bf(a.y); o[2] = f2bf(a.z); o[3] = f2bf(a.w);
    o[4] = f2bf(b.x); o[5] = f2bf(b.y); o[6] = f2bf(b.z); o[7] = f2bf(b.w);
    *(u16v8*)&d[t * 8] = o;
}

// ---------------- RMSNorm: fp32 in -> bf16 out ----------------
__global__ __launch_bounds__(256) void rmsnorm_kernel(
    const float* __restrict__ x, const float* __restrict__ w,
    unsigned short* __restrict__ out)
{
    __shared__ float red[4];
    const int row = blockIdx.x;
    const int tid = threadIdx.x;
    const float* xr = x + (size_t)row * H;
    float4 v0 = ((const float4*)xr)[tid];
    float4 v1 = ((const float4*)xr)[256 + tid];
    float s = v0.x*v0.x + v0.y*v0.y + v0.z*v0.z + v0.w*v0.w
            + v1.x*v1.x + v1.y*v1.y + v1.z*v1.z + v1.w*v1.w;
    #pragma unroll
    for (int o = 1; o < 64; o <<= 1) s += __shfl_xor(s, o);
    if ((tid & 63) == 0) red[tid >> 6] = s;
    __syncthreads();
    float tot = red[0] + red[1] + red[2] + red[3];
    float rinv = rsqrtf(tot * (1.0f / (float)H) + 1e-6f);
    float4 w0 = ((const float4*)w)[tid];
    float4 w1 = ((const float4*)w)[256 + tid];
    u16v4 o0, o1;
    o0[0] = f2bf(v0.x * w0.x * rinv); o0[1] = f2bf(v0.y * w0.y * rinv);
    o0[2] = f2bf(v0.z * w0.z * rinv); o0[3] = f2bf(v0.w * w0.w * rinv);
    o1[0] = f2bf(v1.x * w1.x * rinv); o1[1] = f2bf(v1.y * w1.y * rinv);
    o1[2] = f2bf(v1.z * w1.z * rinv); o1[3] = f2bf(v1.w * w1.w * rinv);
    unsigned short* orow = out + (size_t)row * H;
    *(u16v4*)&orow[tid * 4]        = o0;
    *(u16v4*)&orow[1024 + tid * 4] = o1;
}

// ---------------- GEMM (m97 structure): C[M,N] (+)= A[M,lda](bf16) @ B[.,K](bf16)^T ----
// SILU=true: B rows are interleaved up/gate tiles (w2bf_mlp layout); epilogue
// exchanges gate accs through LDS and writes silu(gate)*up into C[S,II] bf16,
// columns blockIdx.x*64 .. +63.
template<typename OutT, bool ATOMIC, bool SILU>
__global__ __launch_bounds__(256) void gemm_bf16(
    const unsigned short* __restrict__ A, const unsigned short* __restrict__ B,
    OutT* __restrict__ C, int M, int N, int K, int lda, int kslice)
{
    __shared__ unsigned short SM[8192];       // As = SM[0..4095], Bs = SM[4096..8191]
    unsigned short* As = SM;
    unsigned short* Bs = SM + 4096;
    const int tid  = threadIdx.x;
    const int wave = tid >> 6, lane = tid & 63;
    const int quad = lane >> 4, l16 = lane & 15;
    const int m0 = blockIdx.y * 128, n0 = blockIdx.x * 128;
    const int wm = (wave >> 1) * 64, wn = (wave & 1) * 64;
    const int kbeg = blockIdx.z * kslice;

    const int sr = lane >> 2;          // row within 16-row group
    const int sc = (lane & 3) * 8;     // col elems 0,8,16,24
    const unsigned short* Ag0 = A + (size_t)(m0 + wave * 16 + sr) * lda + sc + kbeg;
    const unsigned short* Ag1 = Ag0 + (size_t)64 * lda;
    const unsigned short* Bg0 = B + (size_t)(n0 + wave * 16 + sr) * K + sc + kbeg;
    const unsigned short* Bg1 = Bg0 + (size_t)64 * K;
    const unsigned short* Al0 = &As[(wave * 16) * 32];        // wave-uniform bases
    const unsigned short* Al1 = &As[(64 + wave * 16) * 32];
    const unsigned short* Bl0 = &Bs[(wave * 16) * 32];
    const unsigned short* Bl1 = &Bs[(64 + wave * 16) * 32];

    f32x4 acc[4][4] = {};

    for (int k0 = 0; k0 < kslice; k0 += 32) {
        async16(Ag0 + k0, Al0);
        async16(Ag1 + k0, Al1);
        async16(Bg0 + k0, Bl0);
        async16(Bg1 + k0, Bl1);
        __syncthreads();

        bf16x8 af[4], bfm[4];
        #pragma unroll
        for (int i = 0; i < 4; i++)
            af[i] = *(const bf16x8*)&As[(wm + i * 16 + l16) * 32 + quad * 8];
        #pragma unroll
        for (int i = 0; i < 4; i++)
            bfm[i] = *(const bf16x8*)&Bs[(wn + i * 16 + l16) * 32 + quad * 8];
        #pragma unroll
        for (int mi = 0; mi < 4; mi++)
            #pragma unroll
            for (int ni = 0; ni < 4; ni++)
                acc[mi][ni] = __builtin_amdgcn_mfma_f32_16x16x32_bf16(
                    af[mi], bfm[ni], acc[mi][ni], 0, 0, 0);
        __syncthreads();
    }

    if constexpr (SILU) {
        // gate waves (wn=64) pass accs to up waves (wn=0) via LDS (16 KB reuse)
        if (wave & 1) {
            #pragma unroll
            for (int mi = 0; mi < 4; mi++)
                #pragma unroll
                for (int r = 0; r < 4; r++) {
                    const int lm = wm + mi * 16 + quad * 4 + r;
                    #pragma unroll
                    for (int ni = 0; ni < 4; ni++)
                        SM[lm * 64 + ni * 16 + l16] = f2bf(acc[mi][ni][r]);
                }
        }
        __syncthreads();
        if (!(wave & 1)) {
            const int colbase = blockIdx.x * 64;
            #pragma unroll
            for (int mi = 0; mi < 4; mi++)
                #pragma unroll
                for (int r = 0; r < 4; r++) {
                    const int lm = wm + mi * 16 + quad * 4 + r;
                    const size_t rowoff = (size_t)(m0 + lm) * N;
                    #pragma unroll
                    for (int ni = 0; ni < 4; ni++) {
                        const int c = ni * 16 + l16;
                        float g = bf2f(SM[lm * 64 + c]);
                        float u = acc[mi][ni][r];
                        float sig = 1.0f / (1.0f + exp2f(-g * 1.4426950408889634f));
                        C[rowoff + colbase + c] = f2bf(g * sig * u);
                    }
                }
        }
        return;
    }

    #pragma unroll
    for (int mi = 0; mi < 4; mi++) {
        #pragma unroll
        for (int r = 0; r < 4; r++) {
            const int m = m0 + wm + mi * 16 + quad * 4 + r;
            const size_t rowoff = (size_t)m * N;
            #pragma unroll
            for (int ni = 0; ni < 4; ni++) {
                const int n = n0 + wn + ni * 16 + l16;
                float v = acc[mi][ni][r];
                if constexpr (ATOMIC) {
                    atomicAdd((float*)&C[rowoff + n], v);
                } else if constexpr (std::is_same<OutT, float>::value) {
                    C[rowoff + n] = v;
                } else {
                    C[rowoff + n] = f2bf(v);
                }
            }
        }
    }
}

// ---------------- RoPE prep: qkv fp32 [S,4096] -> q_r [NH,S,HD], k_r [NKV,S,HD] bf16 ----
__global__ __launch_bounds__(256) void rope_prep(
    const float* __restrict__ qkv, const float* __restrict__ cosp,
    const float* __restrict__ sinp,
    unsigned short* __restrict__ q_r, unsigned short* __restrict__ k_r)
{
    const int s = blockIdx.x;
    const int tid = threadIdx.x;
    const float* row = qkv + (size_t)s * 4096;
    #pragma unroll
    for (int j = 0; j < 12; j++) {          // 3072 = q(2048) + k(1024)
        int e = j * 256 + tid;
        int head = e >> 7, hd = e & 127;
        float v = row[e];
        float part = (hd < 64) ? -row[e + 64] : row[e - 64];
        float c  = cosp[s * HD + hd];
        float sn = sinp[s * HD + hd];
        unsigned short ob = f2bf(v * c + part * sn);
        if (head < NH) q_r[((size_t)head * S + s) * HD + hd] = ob;
        else           k_r[((size_t)(head - NH) * S + s) * HD + hd] = ob;
    }
}

// ---------------- V transpose: qkv fp32 cols 3072..4095 -> v_t TILED bf16 ----------
// v_t layout: [NKV][S/32 key-tiles][HD=128][32 keys]  (each tile = contiguous 8 KB)
__global__ __launch_bounds__(256) void v_trans(
    const float* __restrict__ qkv, unsigned short* __restrict__ v_t)
{
    __shared__ unsigned short t[128][66];
    const int s0 = blockIdx.x * 64;
    const int kv = blockIdx.y;
    const int tid = threadIdx.x;
    const float* base = qkv + 3072 + kv * HD;
    #pragma unroll
    for (int i = 0; i < 8; i++) {
        int idx4 = i * 256 + tid;           // one float4 each, 2048 total
        int s_l = idx4 >> 5;
        int hd4 = (idx4 & 31) * 4;
        float4 v = *(const float4*)(base + (size_t)(s0 + s_l) * 4096 + hd4);
        t[hd4 + 0][s_l] = f2bf(v.x);
        t[hd4 + 1][s_l] = f2bf(v.y);
        t[hd4 + 2][s_l] = f2bf(v.z);
        t[hd4 + 3][s_l] = f2bf(v.w);
    }
    __syncthreads();
    // write two key-tiles (32 keys each), tile-contiguous
    #pragma unroll
    for (int i = 0; i < 8; i++) {
        int idx = i * 256 + tid;            // 2048 u16v4 chunks
        int d  = idx >> 4;                  // 0..127
        int rm = idx & 15;
        int hh = rm >> 3;                   // key-tile half 0/1
        int s4 = (rm & 7) * 4;              // 0..28 within tile
        u16v4 o;
        o[0] = t[d][hh * 32 + s4];     o[1] = t[d][hh * 32 + s4 + 1];
        o[2] = t[d][hh * 32 + s4 + 2]; o[3] = t[d][hh * 32 + s4 + 3];
        size_t tile = (size_t)kv * (S / 32) + (s0 >> 5) + hh;
        *(u16v4*)&v_t[(tile * 128 + d) * 32 + s4] = o;
    }
}

// ---------------- Flash attention (LDS-staged K/V, swizzled) ----------------
__global__ __launch_bounds__(256) void attn_kernel(
    const unsigned short* __restrict__ q_r, const unsigned short* __restrict__ k_r,
    const unsigned short* __restrict__ v_t, unsigned short* __restrict__ out)
{
    __shared__ unsigned short Ks[32 * 128];
    __shared__ unsigned short Vs[144 * 32];
    __shared__ unsigned short P[4][16][40];
    const int h = blockIdx.y, kv = h >> 1;
    const int qb0 = blockIdx.x * 64;
    const int tid = threadIdx.x;
    const int wave = tid >> 6, lane = tid & 63, quad = lane >> 4, l16 = lane & 15;
    const int qb = qb0 + wave * 16;
    const unsigned short* Q  = q_r + (size_t)h * S * HD;
    const unsigned short* K  = k_r + (size_t)kv * S * HD;
    const unsigned short* Vh = v_t + (size_t)kv * (S / 32) * (128 * 32);

    // ones rows for the l-sum tile (rows 129..143 zero)
    {
        int e0 = tid * 2;
        Vs[128 * 32 + e0]     = (e0     < 32) ? (unsigned short)0x3F80 : (unsigned short)0;
        Vs[128 * 32 + e0 + 1] = (e0 + 1 < 32) ? (unsigned short)0x3F80 : (unsigned short)0;
    }

    bf16x8 aq[4];
    #pragma unroll
    for (int t = 0; t < 4; t++)
        aq[t] = *(const bf16x8*)&Q[(size_t)(qb + l16) * HD + t * 32 + quad * 8];

    f32x4 o[9] = {};                       // o[8] = row-sum accumulator (l)
    float m_i[4] = { -__builtin_inff(), -__builtin_inff(), -__builtin_inff(), -__builtin_inff() };
    const float SCL = 0.08838834764831845f * 1.4426950408889634f;  // 1/sqrt(HD)*log2(e)
    const int nk = (qb0 >> 5) + 2;

    const int kr  = (lane >> 4);           // K: row within 4-row issue group
    const int kbl = lane & 15;             // K: 16B block within 256B row
    const int vr  = (lane >> 2);           // V: row within 16-row issue group
    const int vbl = lane & 3;              // V: 16B block within 64B row

    for (int kb = 0; kb < nk; kb++) {
        const int kbase = kb * 32;
        const unsigned short* Ktile = K + (size_t)kbase * HD;
        const unsigned short* Vtile = Vh + (size_t)kb * (128 * 32);
        #pragma unroll
        for (int e = 0; e < 2; e++) {
            int r = wave * 8 + e * 4 + kr;
            async16(Ktile + r * 128 + ((kbl ^ (r & 15)) * 8), &Ks[(wave * 8 + e * 4) * 128]);
        }
        #pragma unroll
        for (int e = 0; e < 2; e++) {
            int d = wave * 32 + e * 16 + vr;
            async16(Vtile + d * 32 + ((vbl ^ (d & 3)) * 8), &Vs[(wave * 32 + e * 16) * 32]);
        }
        __syncthreads();   // vmcnt(0) drain: tiles landed

        if (kbase <= qb + 15) {
            f32x4 s0 = {0.f, 0.f, 0.f, 0.f}, s1 = {0.f, 0.f, 0.f, 0.f};
            #pragma unroll
            for (int t = 0; t < 4; t++) {
                int b = t * 4 + quad;
                bf16x8 b0 = *(const bf16x8*)&Ks[l16 * 128 + ((b ^ l16) * 8)];
                bf16x8 b1 = *(const bf16x8*)&Ks[(16 + l16) * 128 + ((b ^ l16) * 8)];
                s0 = __builtin_amdgcn_mfma_f32_16x16x32_bf16(aq[t], b0, s0, 0, 0, 0);
                s1 = __builtin_amdgcn_mfma_f32_16x16x32_bf16(aq[t], b1, s1, 0, 0, 0);
            }
            float alpha[4];
            #pragma unroll
            for (int r = 0; r < 4; r++) {
                const int q = qb + quad * 4 + r;
                float v0 = (kbase + l16      <= q) ? s0[r] * SCL : -__builtin_inff();
                float v1 = (kbase + 16 + l16 <= q) ? s1[r] * SCL : -__builtin_inff();
                float mx = fmaxf(v0, v1);
                #pragma unroll
                for (int d = 1; d < 16; d <<= 1) mx = fmaxf(mx, __shfl_xor(mx, d));
                float nm = fmaxf(m_i[r], mx);
                alpha[r] = exp2f(m_i[r] - nm);
                m_i[r] = nm;
                s0[r] = exp2f(v0 - nm);
                s1[r] = exp2f(v1 - nm);
            }
            #pragma unroll
            for (int ni = 0; ni < 9; ni++)
                #pragma unroll
                for (int r = 0; r < 4; r++) o[ni][r] *= alpha[r];
            #pragma unroll
            for (int r = 0; r < 4; r++) {
                P[wave][quad * 4 + r][l16]      = f2bf(s0[r]);
                P[wave][quad * 4 + r][16 + l16] = f2bf(s1[r]);
            }
            asm volatile("s_waitcnt lgkmcnt(0)" ::: "memory");
            bf16x8 ap = *(const bf16x8*)&P[wave][l16][quad * 8];
            #pragma unroll
            for (int ni = 0; ni < 9; ni++) {
                int d = ni * 16 + l16;
                bf16x8 bv = *(const bf16x8*)&Vs[d * 32 + ((quad ^ (d & 3)) * 8)];
                o[ni] = __builtin_amdgcn_mfma_f32_16x16x32_bf16(ap, bv, o[ni], 0, 0, 0);
            }
        }
        __syncthreads();   // all waves done reading before next tile staged
    }
    #pragma unroll
    for (int r = 0; r < 4; r++) {
        float lsum = __shfl(o[8][r], quad * 16);   // l lives in lane (l16=0, quad)
        const float inv = 1.0f / lsum;
        const int qrow = qb + quad * 4 + r;
        #pragma unroll
        for (int ni = 0; ni < 8; ni++)
            out[(size_t)qrow * (NH * HD) + h * HD + ni * 16 + l16] = f2bf(o[ni][r] * inv);
    }
}

// ---------------- launch ----------------
extern "C" void kernel_launch(void* const* d_in, const int* in_sizes, int n_in,
                              void* d_out, int out_size, void* d_ws, size_t ws_size,
                              hipStream_t stream) {
    const float* hs   = (const float*)d_in[0];   // [1,S,H] fp32
    const float* W    = (const float*)d_in[1];   // flat weights fp32
    const float* ln1  = (const float*)d_in[2];
    const float* ln2  = (const float*)d_in[3];
    const float* cosp = (const float*)d_in[4];   // [S,HD]
    const float* sinp = (const float*)d_in[5];
    float* out = (float*)d_out;                  // [S,H] fp32
    char* ws = (char*)d_ws;

    unsigned short* Wbuf   = (unsigned short*)(ws + 0);                  // 64 MiB staged bf16 weights
    unsigned short* x_norm = (unsigned short*)(ws + (64ull  << 20));     // 8 MiB
    float*          qkv    = (float*)(ws + (72ull  << 20));              // 32 MiB fp32 (split-K atomic)
    unsigned short* act    = (unsigned short*)(ws + (72ull  << 20));     // 32 MiB bf16 (reuses qkv, dead)
    unsigned short* q_r    = (unsigned short*)(ws + (104ull << 20));     // 8 MiB
    unsigned short* k_r    = (unsigned short*)(ws + (112ull << 20));     // 4 MiB
    unsigned short* v_t    = (unsigned short*)(ws + (116ull << 20));     // 4 MiB (tiled)
    unsigned short* attn_o = (unsigned short*)(ws + (120ull << 20));     // 8 MiB

    // 1. stage qkv weights -> bf16 ; input RMSNorm
    w2bf<<<8388608 / 2048, 256, 0, stream>>>(W, Wbuf);
    rmsnorm_kernel<<<S, 256, 0, stream>>>(hs, ln1, x_norm);
    // 2. fused QKV GEMM -> qkv fp32 [S,4096], split-K=2 atomic
    hipMemsetAsync(qkv, 0, (size_t)S * 4096 * sizeof(float), stream);
    gemm_bf16<float, true, false><<<dim3(4096 / 128, S / 128, 2), 256, 0, stream>>>(
        x_norm, Wbuf, qkv, S, 4096, H, H, H / 2);
    // 3. RoPE + layouts
    rope_prep<<<S, 256, 0, stream>>>(qkv, cosp, sinp, q_r, k_r);
    v_trans<<<dim3(S / 64, NKV), 256, 0, stream>>>(qkv, v_t);
    // 4. causal flash attention
    attn_kernel<<<dim3(S / 64, NH), 256, 0, stream>>>(q_r, k_r, v_t, attn_o);
    // 5. O-proj: d_out = hs + attn_o @ o_w^T   (prefill residual, split-K=4 atomic)
    w2bf<<<4194304 / 2048, 256, 0, stream>>>(W + 8388608, Wbuf);
    hipMemcpyAsync(out, hs, (size_t)S * H * sizeof(float), hipMemcpyDeviceToDevice, stream);
    gemm_bf16<float, true, false><<<dim3(H / 128, S / 128, 4), 256, 0, stream>>>(
        attn_o, Wbuf, out, S, H, H, H, H / 4);
    // 6. post RMSNorm
    rmsnorm_kernel<<<S, 256, 0, stream>>>(out, ln2, x_norm);
    // 7. fused up|gate GEMM + SiLU epilogue -> act bf16 [S, II]
    w2bf_mlp<<<2 * II, 256, 0, stream>>>(W + 12582912, Wbuf);
    gemm_bf16<unsigned short, false, true><<<dim3((2 * II) / 128, S / 128, 1), 256, 0, stream>>>(
        x_norm, Wbuf, act, S, II, H, H, H);
    // 8. down-proj: d_out += act @ down_w^T  (split-K=8 atomic; residual already in d_out)
    w2bf<<<16777216 / 2048, 256, 0, stream>>>(W + 46137344, Wbuf);
    gemm_bf16<float, true, false><<<dim3(H / 128, S / 128, 8), 256, 0, stream>>>(
        act, Wbuf, out, S, H, II, II, II / 8);
}

// Round 5
// 926.527 us; speedup vs baseline: 1.0737x; 1.0737x over previous
//
#include <hip/hip_runtime.h>
#include <type_traits>
#include <cstdint>
#include <cstddef>

// ---- types ----
typedef __bf16 bf16x8 __attribute__((ext_vector_type(8)));
typedef float  f32x4  __attribute__((ext_vector_type(4)));
typedef unsigned short u16v4 __attribute__((ext_vector_type(4)));
typedef unsigned short u16v8 __attribute__((ext_vector_type(8)));

#define H    2048
#define NH   16
#define NKV  8
#define HD   128
#define II   8192
#define S    2048

__device__ __forceinline__ unsigned short f2bf(float f) {
    union { float f; unsigned u; } v; v.f = f;
    unsigned r = v.u + 0x7fffu + ((v.u >> 16) & 1u);
    return (unsigned short)(r >> 16);
}
__device__ __forceinline__ float bf2f(unsigned short b) {
    union { unsigned u; float f; } v; v.u = ((unsigned)b) << 16;
    return v.f;
}

// async global->LDS, 16B per lane. LDS dest must be wave-uniform base;
// HW adds lane*16. [m97: this alone was 517->874 TF]
__device__ __forceinline__ void async16(const unsigned short* g, const unsigned short* l) {
    __builtin_amdgcn_global_load_lds(
        (const __attribute__((address_space(1))) void*)g,
        (__attribute__((address_space(3))) void*)l, 16, 0, 0);
}

// ---------------- weight fp32 -> bf16 (8 elems/thread) ----------------
__global__ __launch_bounds__(256) void w2bf(const float* __restrict__ src,
                                            unsigned short* __restrict__ dst)
{
    const size_t i = (size_t)blockIdx.x * 256 + threadIdx.x;
    float4 a = ((const float4*)src)[2 * i];
    float4 b = ((const float4*)src)[2 * i + 1];
    u16v8 o;
    o[0] = f2bf(a.x); o[1] = f2bf(a.y); o[2] = f2bf(a.z); o[3] = f2bf(a.w);
    o[4] = f2bf(b.x); o[5] = f2bf(b.y); o[6] = f2bf(b.z); o[7] = f2bf(b.w);
    ((u16v8*)dst)[i] = o;
}

// ---- mlp weights fp32 -> bf16 with up/gate interleave ----
// src: up [II][H] then gate [II][H].
// dst row p: g=p>>7, r=p&127, half=r>>6 (0=up,1=gate), col c=g*64+(r&63)
// -> each 128-row B-tile g holds up rows c and gate rows of the SAME c.
__global__ __launch_bounds__(256) void w2bf_mlp(const float* __restrict__ src,
                                                unsigned short* __restrict__ dst)
{
    const int p = blockIdx.x;
    const int g = p >> 7, r = p & 127;
    const int half = r >> 6;
    const int c = (g << 6) + (r & 63);
    const float* s = src + ((size_t)half * II + c) * H;
    unsigned short* d = dst + (size_t)p * H;
    const int t = threadIdx.x;
    float4 a = ((const float4*)s)[2 * t];
    float4 b = ((const float4*)s)[2 * t + 1];
    u16v8 o;
    o[0] = f2bf(a.x); o[1] = f2bf(a.y); o[2] = f2bf(a.z); o[3] = f2bf(a.w);
    o[4] = f2bf(b.x); o[5] = f2bf(b.y); o[6] = f2bf(b.z); o[7] = f2bf(b.w);
    *(u16v8*)&d[t * 8] = o;
}

// ---------------- RMSNorm: fp32 in -> bf16 out ----------------
__global__ __launch_bounds__(256) void rmsnorm_kernel(
    const float* __restrict__ x, const float* __restrict__ w,
    unsigned short* __restrict__ out)
{
    __shared__ float red[4];
    const int row = blockIdx.x;
    const int tid = threadIdx.x;
    const float* xr = x + (size_t)row * H;
    float4 v0 = ((const float4*)xr)[tid];
    float4 v1 = ((const float4*)xr)[256 + tid];
    float s = v0.x*v0.x + v0.y*v0.y + v0.z*v0.z + v0.w*v0.w
            + v1.x*v1.x + v1.y*v1.y + v1.z*v1.z + v1.w*v1.w;
    #pragma unroll
    for (int o = 1; o < 64; o <<= 1) s += __shfl_xor(s, o);
    if ((tid & 63) == 0) red[tid >> 6] = s;
    __syncthreads();
    float tot = red[0] + red[1] + red[2] + red[3];
    float rinv = rsqrtf(tot * (1.0f / (float)H) + 1e-6f);
    float4 w0 = ((const float4*)w)[tid];
    float4 w1 = ((const float4*)w)[256 + tid];
    u16v4 o0, o1;
    o0[0] = f2bf(v0.x * w0.x * rinv); o0[1] = f2bf(v0.y * w0.y * rinv);
    o0[2] = f2bf(v0.z * w0.z * rinv); o0[3] = f2bf(v0.w * w0.w * rinv);
    o1[0] = f2bf(v1.x * w1.x * rinv); o1[1] = f2bf(v1.y * w1.y * rinv);
    o1[2] = f2bf(v1.z * w1.z * rinv); o1[3] = f2bf(v1.w * w1.w * rinv);
    unsigned short* orow = out + (size_t)row * H;
    *(u16v4*)&orow[tid * 4]        = o0;
    *(u16v4*)&orow[1024 + tid * 4] = o1;
}

// ---------------- GEMM (m97 structure): C[M,N] (+)= A[M,lda](bf16) @ B[.,K](bf16)^T ----
// SWAP: blockIdx.x = M-tile (so consecutive blocks share one B-tile -> L2/L3
// locality on the big weight matrix). SILU: up/gate interleaved B (w2bf_mlp);
// epilogue exchanges gate accs via LDS, writes silu(g)*u to C[S,II] bf16.
// ATOMIC: fp32 atomicAdd into C; R!=nullptr adds residual on split z==0.
template<typename OutT, bool ATOMIC, bool SILU, bool SWAP>
__global__ __launch_bounds__(256) void gemm_bf16(
    const unsigned short* __restrict__ A, const unsigned short* __restrict__ B,
    OutT* __restrict__ C, const float* __restrict__ R,
    int M, int N, int K, int lda, int kslice)
{
    __shared__ unsigned short SM[8192];       // As = SM[0..4095], Bs = SM[4096..8191]
    unsigned short* As = SM;
    unsigned short* Bs = SM + 4096;
    const int tid  = threadIdx.x;
    const int wave = tid >> 6, lane = tid & 63;
    const int quad = lane >> 4, l16 = lane & 15;
    const int nt = SWAP ? blockIdx.y : blockIdx.x;
    const int mt = SWAP ? blockIdx.x : blockIdx.y;
    const int m0 = mt * 128, n0 = nt * 128;
    const int wm = (wave >> 1) * 64, wn = (wave & 1) * 64;
    const int kbeg = blockIdx.z * kslice;

    const int sr = lane >> 2;          // row within 16-row group
    const int sc = (lane & 3) * 8;     // col elems 0,8,16,24
    const unsigned short* Ag0 = A + (size_t)(m0 + wave * 16 + sr) * lda + sc + kbeg;
    const unsigned short* Ag1 = Ag0 + (size_t)64 * lda;
    const unsigned short* Bg0 = B + (size_t)(n0 + wave * 16 + sr) * K + sc + kbeg;
    const unsigned short* Bg1 = Bg0 + (size_t)64 * K;
    const unsigned short* Al0 = &As[(wave * 16) * 32];        // wave-uniform bases
    const unsigned short* Al1 = &As[(64 + wave * 16) * 32];
    const unsigned short* Bl0 = &Bs[(wave * 16) * 32];
    const unsigned short* Bl1 = &Bs[(64 + wave * 16) * 32];

    f32x4 acc[4][4] = {};

    for (int k0 = 0; k0 < kslice; k0 += 32) {
        async16(Ag0 + k0, Al0);
        async16(Ag1 + k0, Al1);
        async16(Bg0 + k0, Bl0);
        async16(Bg1 + k0, Bl1);
        __syncthreads();

        bf16x8 af[4], bfm[4];
        #pragma unroll
        for (int i = 0; i < 4; i++)
            af[i] = *(const bf16x8*)&As[(wm + i * 16 + l16) * 32 + quad * 8];
        #pragma unroll
        for (int i = 0; i < 4; i++)
            bfm[i] = *(const bf16x8*)&Bs[(wn + i * 16 + l16) * 32 + quad * 8];
        #pragma unroll
        for (int mi = 0; mi < 4; mi++)
            #pragma unroll
            for (int ni = 0; ni < 4; ni++)
                acc[mi][ni] = __builtin_amdgcn_mfma_f32_16x16x32_bf16(
                    af[mi], bfm[ni], acc[mi][ni], 0, 0, 0);
        __syncthreads();
    }

    if constexpr (SILU) {
        // gate waves (wn=64) pass accs to up waves (wn=0) via LDS (16 KB reuse)
        if (wave & 1) {
            #pragma unroll
            for (int mi = 0; mi < 4; mi++)
                #pragma unroll
                for (int r = 0; r < 4; r++) {
                    const int lm = wm + mi * 16 + quad * 4 + r;
                    #pragma unroll
                    for (int ni = 0; ni < 4; ni++)
                        SM[lm * 64 + ni * 16 + l16] = f2bf(acc[mi][ni][r]);
                }
        }
        __syncthreads();
        if (!(wave & 1)) {
            const int colbase = nt * 64;
            #pragma unroll
            for (int mi = 0; mi < 4; mi++)
                #pragma unroll
                for (int r = 0; r < 4; r++) {
                    const int lm = wm + mi * 16 + quad * 4 + r;
                    const size_t rowoff = (size_t)(m0 + lm) * N;
                    #pragma unroll
                    for (int ni = 0; ni < 4; ni++) {
                        const int c = ni * 16 + l16;
                        float g = bf2f(SM[lm * 64 + c]);
                        float u = acc[mi][ni][r];
                        float sig = 1.0f / (1.0f + exp2f(-g * 1.4426950408889634f));
                        C[rowoff + colbase + c] = f2bf(g * sig * u);
                    }
                }
        }
        return;
    }

    #pragma unroll
    for (int mi = 0; mi < 4; mi++) {
        #pragma unroll
        for (int r = 0; r < 4; r++) {
            const int m = m0 + wm + mi * 16 + quad * 4 + r;
            const size_t rowoff = (size_t)m * N;
            #pragma unroll
            for (int ni = 0; ni < 4; ni++) {
                const int n = n0 + wn + ni * 16 + l16;
                float v = acc[mi][ni][r];
                if constexpr (ATOMIC) {
                    if (R != nullptr && blockIdx.z == 0) v += R[rowoff + n];
                    atomicAdd((float*)&C[rowoff + n], v);
                } else if constexpr (std::is_same<OutT, float>::value) {
                    C[rowoff + n] = v;
                } else {
                    C[rowoff + n] = f2bf(v);
                }
            }
        }
    }
}

// ---------------- RoPE prep: qkv bf16 [S,4096] -> q_r [NH,S,HD], k_r [NKV,S,HD] bf16 ----
__global__ __launch_bounds__(256) void rope_prep(
    const unsigned short* __restrict__ qkv, const float* __restrict__ cosp,
    const float* __restrict__ sinp,
    unsigned short* __restrict__ q_r, unsigned short* __restrict__ k_r)
{
    const int s = blockIdx.x;
    const int tid = threadIdx.x;
    const unsigned short* row = qkv + (size_t)s * 4096;
    #pragma unroll
    for (int j = 0; j < 12; j++) {          // 3072 = q(2048) + k(1024)
        int e = j * 256 + tid;
        int head = e >> 7, hd = e & 127;
        float v = bf2f(row[e]);
        float part = (hd < 64) ? -bf2f(row[e + 64]) : bf2f(row[e - 64]);
        float c  = cosp[s * HD + hd];
        float sn = sinp[s * HD + hd];
        unsigned short ob = f2bf(v * c + part * sn);
        if (head < NH) q_r[((size_t)head * S + s) * HD + hd] = ob;
        else           k_r[((size_t)(head - NH) * S + s) * HD + hd] = ob;
    }
}

// ---------------- V transpose: qkv bf16 cols 3072..4095 -> v_t TILED bf16 ----------
// v_t layout: [NKV][S/32 key-tiles][HD=128][32 keys]  (each tile = contiguous 8 KB)
__global__ __launch_bounds__(256) void v_trans(
    const unsigned short* __restrict__ qkv, unsigned short* __restrict__ v_t)
{
    __shared__ unsigned short t[128][66];
    const int s0 = blockIdx.x * 64;
    const int kv = blockIdx.y;
    const int tid = threadIdx.x;
    const unsigned short* base = qkv + 3072 + kv * HD;
    #pragma unroll
    for (int i = 0; i < 4; i++) {
        int idx = i * 256 + tid;            // one u16v8 each, 1024 total
        int s_l = idx >> 4;
        int hd8 = (idx & 15) * 8;
        u16v8 v = *(const u16v8*)(base + (size_t)(s0 + s_l) * 4096 + hd8);
        #pragma unroll
        for (int j = 0; j < 8; j++) t[hd8 + j][s_l] = v[j];
    }
    __syncthreads();
    #pragma unroll
    for (int i = 0; i < 8; i++) {
        int idx = i * 256 + tid;            // 2048 u16v4 chunks
        int d  = idx >> 4;                  // 0..127
        int rm = idx & 15;
        int hh = rm >> 3;                   // key-tile half 0/1
        int s4 = (rm & 7) * 4;              // 0..28 within tile
        u16v4 o;
        o[0] = t[d][hh * 32 + s4];     o[1] = t[d][hh * 32 + s4 + 1];
        o[2] = t[d][hh * 32 + s4 + 2]; o[3] = t[d][hh * 32 + s4 + 3];
        size_t tile = (size_t)kv * (S / 32) + (s0 >> 5) + hh;
        *(u16v4*)&v_t[(tile * 128 + d) * 32 + s4] = o;
    }
}

// ---------------- Flash attention (LDS-staged K/V, swizzled) ----------------
__global__ __launch_bounds__(256) void attn_kernel(
    const unsigned short* __restrict__ q_r, const unsigned short* __restrict__ k_r,
    const unsigned short* __restrict__ v_t, unsigned short* __restrict__ out)
{
    __shared__ unsigned short Ks[32 * 128];
    __shared__ unsigned short Vs[144 * 32];
    __shared__ unsigned short P[4][16][40];
    const int h = blockIdx.y, kv = h >> 1;
    const int qb0 = blockIdx.x * 64;
    const int tid = threadIdx.x;
    const int wave = tid >> 6, lane = tid & 63, quad = lane >> 4, l16 = lane & 15;
    const int qb = qb0 + wave * 16;
    const unsigned short* Q  = q_r + (size_t)h * S * HD;
    const unsigned short* K  = k_r + (size_t)kv * S * HD;
    const unsigned short* Vh = v_t + (size_t)kv * (S / 32) * (128 * 32);

    // ones rows for the l-sum tile (rows 129..143 zero)
    {
        int e0 = tid * 2;
        Vs[128 * 32 + e0]     = (e0     < 32) ? (unsigned short)0x3F80 : (unsigned short)0;
        Vs[128 * 32 + e0 + 1] = (e0 + 1 < 32) ? (unsigned short)0x3F80 : (unsigned short)0;
    }

    bf16x8 aq[4];
    #pragma unroll
    for (int t = 0; t < 4; t++)
        aq[t] = *(const bf16x8*)&Q[(size_t)(qb + l16) * HD + t * 32 + quad * 8];

    f32x4 o[9] = {};                       // o[8] = row-sum accumulator (l)
    float m_i[4] = { -__builtin_inff(), -__builtin_inff(), -__builtin_inff(), -__builtin_inff() };
    const float SCL = 0.08838834764831845f * 1.4426950408889634f;  // 1/sqrt(HD)*log2(e)
    const int nk = (qb0 >> 5) + 2;

    const int kr  = (lane >> 4);           // K: row within 4-row issue group
    const int kbl = lane & 15;             // K: 16B block within 256B row
    const int vr  = (lane >> 2);           // V: row within 16-row issue group
    const int vbl = lane & 3;              // V: 16B block within 64B row

    for (int kb = 0; kb < nk; kb++) {
        const int kbase = kb * 32;
        const unsigned short* Ktile = K + (size_t)kbase * HD;
        const unsigned short* Vtile = Vh + (size_t)kb * (128 * 32);
        #pragma unroll
        for (int e = 0; e < 2; e++) {
            int r = wave * 8 + e * 4 + kr;
            async16(Ktile + r * 128 + ((kbl ^ (r & 15)) * 8), &Ks[(wave * 8 + e * 4) * 128]);
        }
        #pragma unroll
        for (int e = 0; e < 2; e++) {
            int d = wave * 32 + e * 16 + vr;
            async16(Vtile + d * 32 + ((vbl ^ (d & 3)) * 8), &Vs[(wave * 32 + e * 16) * 32]);
        }
        __syncthreads();   // vmcnt(0) drain: tiles landed

        if (kbase <= qb + 15) {
            f32x4 s0 = {0.f, 0.f, 0.f, 0.f}, s1 = {0.f, 0.f, 0.f, 0.f};
            #pragma unroll
            for (int t = 0; t < 4; t++) {
                int b = t * 4 + quad;
                bf16x8 b0 = *(const bf16x8*)&Ks[l16 * 128 + ((b ^ l16) * 8)];
                bf16x8 b1 = *(const bf16x8*)&Ks[(16 + l16) * 128 + ((b ^ l16) * 8)];
                s0 = __builtin_amdgcn_mfma_f32_16x16x32_bf16(aq[t], b0, s0, 0, 0, 0);
                s1 = __builtin_amdgcn_mfma_f32_16x16x32_bf16(aq[t], b1, s1, 0, 0, 0);
            }
            float alpha[4];
            #pragma unroll
            for (int r = 0; r < 4; r++) {
                const int q = qb + quad * 4 + r;
                float v0 = (kbase + l16      <= q) ? s0[r] * SCL : -__builtin_inff();
                float v1 = (kbase + 16 + l16 <= q) ? s1[r] * SCL : -__builtin_inff();
                float mx = fmaxf(v0, v1);
                #pragma unroll
                for (int d = 1; d < 16; d <<= 1) mx = fmaxf(mx, __shfl_xor(mx, d));
                float nm = fmaxf(m_i[r], mx);
                alpha[r] = exp2f(m_i[r] - nm);
                m_i[r] = nm;
                s0[r] = exp2f(v0 - nm);
                s1[r] = exp2f(v1 - nm);
            }
            #pragma unroll
            for (int ni = 0; ni < 9; ni++)
                #pragma unroll
                for (int r = 0; r < 4; r++) o[ni][r] *= alpha[r];
            #pragma unroll
            for (int r = 0; r < 4; r++) {
                P[wave][quad * 4 + r][l16]      = f2bf(s0[r]);
                P[wave][quad * 4 + r][16 + l16] = f2bf(s1[r]);
            }
            asm volatile("s_waitcnt lgkmcnt(0)" ::: "memory");
            bf16x8 ap = *(const bf16x8*)&P[wave][l16][quad * 8];
            #pragma unroll
            for (int ni = 0; ni < 9; ni++) {
                int d = ni * 16 + l16;
                bf16x8 bv = *(const bf16x8*)&Vs[d * 32 + ((quad ^ (d & 3)) * 8)];
                o[ni] = __builtin_amdgcn_mfma_f32_16x16x32_bf16(ap, bv, o[ni], 0, 0, 0);
            }
        }
        __syncthreads();   // all waves done reading before next tile staged
    }
    #pragma unroll
    for (int r = 0; r < 4; r++) {
        float lsum = __shfl(o[8][r], quad * 16);   // l lives in lane (l16=0, quad)
        const float inv = 1.0f / lsum;
        const int qrow = qb + quad * 4 + r;
        #pragma unroll
        for (int ni = 0; ni < 8; ni++)
            out[(size_t)qrow * (NH * HD) + h * HD + ni * 16 + l16] = f2bf(o[ni][r] * inv);
    }
}

// ---------------- launch ----------------
extern "C" void kernel_launch(void* const* d_in, const int* in_sizes, int n_in,
                              void* d_out, int out_size, void* d_ws, size_t ws_size,
                              hipStream_t stream) {
    const float* hs   = (const float*)d_in[0];   // [1,S,H] fp32
    const float* W    = (const float*)d_in[1];   // flat weights fp32
    const float* ln1  = (const float*)d_in[2];
    const float* ln2  = (const float*)d_in[3];
    const float* cosp = (const float*)d_in[4];   // [S,HD]
    const float* sinp = (const float*)d_in[5];
    float* out = (float*)d_out;                  // [S,H] fp32
    char* ws = (char*)d_ws;

    unsigned short* Wbuf   = (unsigned short*)(ws + 0);                  // 64 MiB staged bf16 weights
    unsigned short* x_norm = (unsigned short*)(ws + (64ull  << 20));     // 8 MiB
    unsigned short* qkv    = (unsigned short*)(ws + (72ull  << 20));     // 16 MiB bf16
    unsigned short* act    = (unsigned short*)(ws + (72ull  << 20));     // 32 MiB bf16 (reuses qkv, dead)
    unsigned short* q_r    = (unsigned short*)(ws + (104ull << 20));     // 8 MiB
    unsigned short* k_r    = (unsigned short*)(ws + (112ull << 20));     // 4 MiB
    unsigned short* v_t    = (unsigned short*)(ws + (116ull << 20));     // 4 MiB (tiled)
    unsigned short* attn_o = (unsigned short*)(ws + (120ull << 20));     // 8 MiB

    // 1. stage qkv weights -> bf16 ; input RMSNorm
    w2bf<<<8388608 / 2048, 256, 0, stream>>>(W, Wbuf);
    rmsnorm_kernel<<<S, 256, 0, stream>>>(hs, ln1, x_norm);
    // 2. fused QKV GEMM -> qkv bf16 [S,4096]  (SWAP: adjacent blocks share B-tile)
    gemm_bf16<unsigned short, false, false, true><<<dim3(S / 128, 4096 / 128, 1), 256, 0, stream>>>(
        x_norm, Wbuf, qkv, nullptr, S, 4096, H, H, H);
    // 3. RoPE + layouts
    rope_prep<<<S, 256, 0, stream>>>(qkv, cosp, sinp, q_r, k_r);
    v_trans<<<dim3(S / 64, NKV), 256, 0, stream>>>(qkv, v_t);
    // 4. causal flash attention
    attn_kernel<<<dim3(S / 64, NH), 256, 0, stream>>>(q_r, k_r, v_t, attn_o);
    // 5. O-proj: d_out = hs + attn_o @ o_w^T  (memset + split-K=2 atomic, z0 adds hs)
    w2bf<<<4194304 / 2048, 256, 0, stream>>>(W + 8388608, Wbuf);
    hipMemsetAsync(out, 0, (size_t)S * H * sizeof(float), stream);
    gemm_bf16<float, true, false, false><<<dim3(H / 128, S / 128, 2), 256, 0, stream>>>(
        attn_o, Wbuf, out, hs, S, H, H, H, H / 2);
    // 6. post RMSNorm
    rmsnorm_kernel<<<S, 256, 0, stream>>>(out, ln2, x_norm);
    // 7. fused up|gate GEMM + SiLU epilogue -> act bf16 [S, II]  (SWAP for B locality)
    w2bf_mlp<<<2 * II, 256, 0, stream>>>(W + 12582912, Wbuf);
    gemm_bf16<unsigned short, false, true, true><<<dim3(S / 128, (2 * II) / 128, 1), 256, 0, stream>>>(
        x_norm, Wbuf, act, nullptr, S, II, H, H, H);
    // 8. down-proj: d_out += act @ down_w^T  (split-K=4 atomic; residual already in d_out)
    w2bf<<<16777216 / 2048, 256, 0, stream>>>(W + 46137344, Wbuf);
    gemm_bf16<float, true, false, false><<<dim3(H / 128, S / 128, 4), 256, 0, stream>>>(
        act, Wbuf, out, nullptr, S, H, II, II, II / 4);
}